// Round 6
// baseline (334.108 us; speedup 1.0000x reference)
//
#include <hip/hip_runtime.h>

// RSCA fully-fused, round-6 (= round-5 resubmit after infra failure).
// Structure = round-3 (grid 2048, TC=4 cols/block, inter-block pool/attn
// overlap). Key change vs round-3: the exp pipe was the measured wall
// (v_exp_f32 ~16 cyc/wave64, ~55us of trans occupancy; backed out from R0's
// VALUBusy=50% @121us with the instruction census). Half the exps now run as
// rndne + packed Taylor-4 (f in [-0.5,0.5], rel err <=4.5e-5) + ldexp on the
// full-rate VALU pipe; the other half stay on v_exp. Balanced halves keep both
// pipes busy whether or not trans co-issues with VALU across waves.
// Retained: raw-only LDS + k-affine folded into per-query constants, v2f pk
// math, register double-buffered j-loop, shuffle minmax, padded LDS strides,
// XCD-swizzled contiguous columns, obuf float4 flush, launch_bounds(256,5).

constexpr int B_SEQ = 128;
constexpr int N_COL = 8192;
constexpr int HWP   = 49;
constexpr int NT    = 256;
constexpr int TC    = 4;
constexpr int VSTR  = 132;   // value-array stride: spreads banks, rows 16B-aligned
constexpr int OSTR  = 5;     // obuf stride: gcd(5,32)=1 -> conflict-free

typedef float v2f __attribute__((ext_vector_type(2)));

#if __has_builtin(__builtin_elementwise_fma)
#define VFMA(a, b, c) __builtin_elementwise_fma((a), (b), (c))
#else
__device__ __forceinline__ v2f VFMA(v2f a, v2f b, v2f c) {
    v2f r; r.x = fmaf(a.x, b.x, c.x); r.y = fmaf(a.y, b.y, c.y); return r;
}
#endif

// 2^t for t <= 0 (max-subtracted scores), packed, VALU-pipe only.
// n = rndne(t); f = t-n in [-0.5,0.5]; 2^f by Taylor-4 (rel err <= 4.5e-5);
// scale by 2^n via v_ldexp_f32 (graceful underflow -> 0 for tiny weights).
__device__ __forceinline__ v2f exp2_poly(v2f t) {
    const float nx = __builtin_rintf(t.x);
    const float ny = __builtin_rintf(t.y);
    v2f f; f.x = t.x - nx; f.y = t.y - ny;
    const v2f c4 = {0.0096181291f, 0.0096181291f};
    const v2f c3 = {0.0555041087f, 0.0555041087f};
    const v2f c2 = {0.2402265070f, 0.2402265070f};
    const v2f c1 = {0.6931471806f, 0.6931471806f};
    const v2f c0 = {1.0f, 1.0f};
    v2f p = VFMA(c4, f, c3);
    p = VFMA(p, f, c2);
    p = VFMA(p, f, c1);
    p = VFMA(p, f, c0);
    v2f e; e.x = ldexpf(p.x, (int)nx);
           e.y = ldexpf(p.y, (int)ny);
    return e;
}

__global__ __launch_bounds__(NT, 5) void rsca_fused(
    const float* __restrict__ x, const float* __restrict__ y,
    const float* __restrict__ pwq, const float* __restrict__ pwk,
    const float* __restrict__ pwv, const float* __restrict__ pbq,
    const float* __restrict__ pbk, const float* __restrict__ pbv,
    const float* __restrict__ pwo, const float* __restrict__ pbo,
    float* __restrict__ out)
{
    __shared__ float xv[TC * VSTR];          // raw pooled means, [c*VSTR + j]
    __shared__ float yv[TC * VSTR];          // raw y,           [c*VSTR + j]
    __shared__ float pmnx[8][TC], pmxx[8][TC];   // x partials: pass*4+wave
    __shared__ float pmny[4][TC], pmxy[4][TC];   // y partials: wave
    __shared__ float obuf[2][B_SEQ * OSTR];

    const int t    = threadIdx.x;
    const int bid  = blockIdx.x;
    // same-XCD contiguous columns: 4 adjacent cg's (sharing a 64B out line)
    // are on one XCD -> L2 write-merge.
    const int cg = (bid & 7) * ((N_COL / TC) >> 3) + (bid >> 3);
    const int n0 = cg * TC;

    const int ql   = t & 3;
    const int seg  = t >> 2;
    const int lane = t & 63;
    const int wid  = t >> 6;

    const float wq = pwq[0], wk = pwk[0], wv = pwv[0];
    const float bq = pbq[0], bk = pbk[0], bv = pbv[0];
    const float wo = pwo[0], bo = pbo[0];
    const float L2E = 1.4426950408889634f;
    const float wkL = wk * L2E, bkL = bk * L2E;
    const float alpha = wo * wv;
    const float beta2 = 2.0f * (wo * bv + bo);

    // ---- stage y (raw) + wave-partial min/max ----
    {
        const int j = t >> 2, c = t & 3;
        const float fy0 = y[(size_t)j * N_COL + n0 + c];
        const float fy1 = y[(size_t)(j + 64) * N_COL + n0 + c];
        yv[c * VSTR + j]      = fy0;
        yv[c * VSTR + j + 64] = fy1;
        float mn = fminf(fy0, fy1), mx = fmaxf(fy0, fy1);
        #pragma unroll
        for (int off = 4; off <= 32; off <<= 1) {
            mn = fminf(mn, __shfl_xor(mn, off));
            mx = fmaxf(mx, __shfl_xor(mx, off));
        }
        if (lane < 4) { pmny[wid][lane] = mn; pmxy[wid][lane] = mx; }
    }

    // ---- pool x -> xv (raw means) + wave-partial min/max ----
    for (int pass = 0; pass < 2; ++pass) {
        const int j = pass * 64 + seg;
        const float4* __restrict__ base =
            (const float4*)(x + ((size_t)j * N_COL + n0) * (size_t)HWP);
        float4 v[13];
        #pragma unroll
        for (int k = 0; k < 12; ++k) v[k] = base[ql + 4 * k];
        v[12] = base[48];

        float s0 = 0.f, s1 = 0.f, s2 = 0.f, s3 = 0.f;
        s0 += v[0].x + v[0].y + v[0].z + v[0].w;
        s0 += v[1].x + v[1].y + v[1].z + v[1].w;
        s0 += v[2].x + v[2].y + v[2].z + v[2].w;
        s1 += v[4].x + v[4].y + v[4].z + v[4].w;
        s1 += v[5].x + v[5].y + v[5].z + v[5].w;
        s2 += v[7].x + v[7].y + v[7].z + v[7].w;
        s2 += v[8].x + v[8].y + v[8].z + v[8].w;
        s3 += v[10].x + v[10].y + v[10].z + v[10].w;
        s3 += v[11].x + v[11].y + v[11].z + v[11].w;
        { const float sm = v[3].x + v[3].y + v[3].z + v[3].w;
          const float cr = (ql == 0) ? v[3].x : 0.0f;
          s0 += cr; s1 += sm - cr; }
        { const float sm = v[6].x + v[6].y + v[6].z + v[6].w;
          const float cr = (ql == 0) ? (v[6].x + v[6].y) : 0.0f;
          s1 += cr; s2 += sm - cr; }
        { const float sm = v[9].x + v[9].y + v[9].z + v[9].w;
          const float cr = (ql == 0) ? (v[9].x + v[9].y + v[9].z) : 0.0f;
          s2 += cr; s3 += sm - cr; }
        const float tail = v[12].x + v[12].y + v[12].z + v[12].w;

        s0 += __shfl_xor(s0, 1); s1 += __shfl_xor(s1, 1);
        s2 += __shfl_xor(s2, 1); s3 += __shfl_xor(s3, 1);
        s0 += __shfl_xor(s0, 2); s1 += __shfl_xor(s1, 2);
        s2 += __shfl_xor(s2, 2); s3 += __shfl_xor(s3, 2);
        float r = s0;
        r = (ql == 1) ? s1 : r;
        r = (ql == 2) ? s2 : r;
        r = (ql == 3) ? (s3 + tail) : r;
        const float mean = r * (1.0f / HWP);
        xv[ql * VSTR + j] = mean;

        float mn = mean, mx = mean;
        #pragma unroll
        for (int off = 4; off <= 32; off <<= 1) {
            mn = fminf(mn, __shfl_xor(mn, off));
            mx = fmaxf(mx, __shfl_xor(mx, off));
        }
        if (lane < 4) {
            pmnx[pass * 4 + wid][lane] = mn;
            pmxx[pass * 4 + wid][lane] = mx;
        }
    }
    __syncthreads();

    // ---- attention: thread = (query i, half ch); 2 columns each ----
    const int i  = t & (B_SEQ - 1);
    const int ch = t >> 7;
    #pragma unroll
    for (int cc = 0; cc < 2; ++cc) {
        const int c = ch * 2 + cc;                  // wave-uniform -> LDS broadcast
        const float* __restrict__ vx = &xv[c * VSTR];
        const float* __restrict__ vy = &yv[c * VSTR];

        float vxmn = pmnx[0][c], vxmx = pmxx[0][c];
        #pragma unroll
        for (int s = 1; s < 8; ++s) {
            vxmn = fminf(vxmn, pmnx[s][c]);
            vxmx = fmaxf(vxmx, pmxx[s][c]);
        }
        float vymn = pmny[0][c], vymx = pmxy[0][c];
        #pragma unroll
        for (int s = 1; s < 4; ++s) {
            vymn = fminf(vymn, pmny[s][c]);
            vymx = fmaxf(vymx, pmxy[s][c]);
        }
        const float axv = fmaf(vxmx, wkL, bkL), bxv = fmaf(vxmn, wkL, bkL);
        const float kxmx = fmaxf(axv, bxv), kxmn = fminf(axv, bxv);
        const float ayv = fmaf(vymx, wkL, bkL), byv = fmaf(vymn, wkL, bkL);
        const float kymx = fmaxf(ayv, byv), kymn = fminf(ayv, byv);

        const float xi = vx[i], yi = vy[i];
        const float qx = fmaf(xi, wq, bq), qy = fmaf(yi, wq, bq);
        const float nmsx = -(qx >= 0.f ? qx * kxmx : qx * kxmn);
        const float nmcy = -(qy >= 0.f ? qy * kxmx : qy * kxmn);
        const float nmsy = -(qy >= 0.f ? qy * kymx : qy * kymn);
        const float nmcx = -(qx >= 0.f ? qx * kymx : qx * kymn);

        // score*log2e = v*(q*wkL) + (q*bkL + nm)
        const float qxw = qx * wkL, qyw = qy * wkL;
        const v2f qxw2 = {qxw, qxw}, qyw2 = {qyw, qyw};
        const float csx = fmaf(qx, bkL, nmsx), ccy = fmaf(qy, bkL, nmcy);
        const float csy = fmaf(qy, bkL, nmsy), ccx = fmaf(qx, bkL, nmcx);
        const v2f csx2 = {csx, csx}, ccy2 = {ccy, ccy};
        const v2f csy2 = {csy, csy}, ccx2 = {ccx, ccx};

        v2f s0sx = {0.f, 0.f}, s1sx = {0.f, 0.f};
        v2f s0cy = {0.f, 0.f}, s1cy = {0.f, 0.f};
        v2f s0sy = {0.f, 0.f}, s1sy = {0.f, 0.f};
        v2f s0cx = {0.f, 0.f}, s1cx = {0.f, 0.f};

        // trans-pipe variants (v_exp_f32)
        auto px2T = [&](float v0, float v1) {
            const v2f vvj = {v0, v1};
            v2f t1 = VFMA(qxw2, vvj, csx2);
            v2f e1; e1.x = __builtin_amdgcn_exp2f(t1.x);
                    e1.y = __builtin_amdgcn_exp2f(t1.y);
            s1sx = VFMA(e1, vvj, s1sx); s0sx += e1;
            v2f t2 = VFMA(qyw2, vvj, ccy2);
            v2f e2; e2.x = __builtin_amdgcn_exp2f(t2.x);
                    e2.y = __builtin_amdgcn_exp2f(t2.y);
            s1cy = VFMA(e2, vvj, s1cy); s0cy += e2;
        };
        auto py2T = [&](float v0, float v1) {
            const v2f vvj = {v0, v1};
            v2f t3 = VFMA(qyw2, vvj, csy2);
            v2f e3; e3.x = __builtin_amdgcn_exp2f(t3.x);
                    e3.y = __builtin_amdgcn_exp2f(t3.y);
            s1sy = VFMA(e3, vvj, s1sy); s0sy += e3;
            v2f t4 = VFMA(qxw2, vvj, ccx2);
            v2f e4; e4.x = __builtin_amdgcn_exp2f(t4.x);
                    e4.y = __builtin_amdgcn_exp2f(t4.y);
            s1cx = VFMA(e4, vvj, s1cx); s0cx += e4;
        };
        // VALU-pipe variants (packed poly)
        auto px2P = [&](float v0, float v1) {
            const v2f vvj = {v0, v1};
            v2f e1 = exp2_poly(VFMA(qxw2, vvj, csx2));
            s1sx = VFMA(e1, vvj, s1sx); s0sx += e1;
            v2f e2 = exp2_poly(VFMA(qyw2, vvj, ccy2));
            s1cy = VFMA(e2, vvj, s1cy); s0cy += e2;
        };
        auto py2P = [&](float v0, float v1) {
            const v2f vvj = {v0, v1};
            v2f e3 = exp2_poly(VFMA(qyw2, vvj, csy2));
            s1sy = VFMA(e3, vvj, s1sy); s0sy += e3;
            v2f e4 = exp2_poly(VFMA(qxw2, vvj, ccx2));
            s1cx = VFMA(e4, vvj, s1cx); s0cx += e4;
        };

        // register double-buffer: load j0+8 before computing j0's body.
        // Alternate trans/poly per j-quad: both pipes fed within each chunk.
        float4 a0 = *(const float4*)&vx[0], a1 = *(const float4*)&vx[4];
        float4 b0 = *(const float4*)&vy[0], b1 = *(const float4*)&vy[4];
        for (int j0 = 0; j0 < B_SEQ; j0 += 8) {
            const int jn = (j0 + 8) & (B_SEQ - 1);     // wraps on last iter (dummy)
            float4 na0 = *(const float4*)&vx[jn];
            float4 na1 = *(const float4*)&vx[jn + 4];
            float4 nb0 = *(const float4*)&vy[jn];
            float4 nb1 = *(const float4*)&vy[jn + 4];

            px2T(a0.x, a0.y); px2P(a0.z, a0.w);
            px2T(a1.x, a1.y); px2P(a1.z, a1.w);
            py2T(b0.x, b0.y); py2P(b0.z, b0.w);
            py2T(b1.x, b1.y); py2P(b1.z, b1.w);

            a0 = na0; a1 = na1; b0 = nb0; b1 = nb1;
        }
        const float S0sx = s0sx.x + s0sx.y, S1sx = s1sx.x + s1sx.y;
        const float S0cy = s0cy.x + s0cy.y, S1cy = s1cy.x + s1cy.y;
        const float S0sy = s0sy.x + s0sy.y, S1sy = s1sy.x + s1sy.y;
        const float S0cx = s0cx.x + s0cx.y, S1cx = s1cx.x + s1cx.y;
        const float mx_attn = S1sx * __builtin_amdgcn_rcpf(S0sx)
                            + S1cx * __builtin_amdgcn_rcpf(S0cx);
        const float my_attn = S1sy * __builtin_amdgcn_rcpf(S0sy)
                            + S1cy * __builtin_amdgcn_rcpf(S0cy);
        obuf[0][i * OSTR + c] = fmaf(alpha, mx_attn, beta2 + xi);
        obuf[1][i * OSTR + c] = fmaf(alpha, my_attn, beta2 + yi);
    }
    __syncthreads();

    // ---- flush: one float4 per thread, 16B row segments (L2 merges 4 blocks
    // of the same XCD into 64B lines) ----
    {
        const int set = t >> 7;
        const int ii  = t & (B_SEQ - 1);
        const float* p = &obuf[set][ii * OSTR];
        float4 val;
        val.x = p[0]; val.y = p[1]; val.z = p[2]; val.w = p[3];
        *(float4*)&out[(size_t)ii * (2 * N_COL) + (size_t)set * N_COL + n0] = val;
    }
}

extern "C" void kernel_launch(void* const* d_in, const int* in_sizes, int n_in,
                              void* d_out, int out_size, void* d_ws, size_t ws_size,
                              hipStream_t stream) {
    const float* x   = (const float*)d_in[0];
    const float* y   = (const float*)d_in[1];
    const float* pwq = (const float*)d_in[2];
    const float* pwk = (const float*)d_in[3];
    const float* pwv = (const float*)d_in[4];
    const float* pbq = (const float*)d_in[5];
    const float* pbk = (const float*)d_in[6];
    const float* pbv = (const float*)d_in[7];
    const float* pwo = (const float*)d_in[8];
    const float* pbo = (const float*)d_in[9];
    float* out = (float*)d_out;

    rsca_fused<<<dim3(N_COL / TC), dim3(NT), 0, stream>>>(
        x, y, pwq, pwk, pwv, pbq, pbk, pbv, pwo, pbo, out);
}

// Round 7
// 318.784 us; speedup vs baseline: 1.0481x; 1.0481x over previous
//
#include <hip/hip_runtime.h>

// RSCA fully-fused, round-7. Poly-exp REVERTED (R6 measured v_exp ~6cyc/wave:
// poly's 12cyc/exp of VALU made it strictly worse, +23us VALUBusy for -11us
// trans). New lever: parity phase-offset. Co-resident blocks on a CU are
// consecutive bid>>8 slots, so par=(bid>>8)&1 mixes both parities on every CU:
//   par 0: pool -> passY -> passX   (HBM streaming starts at t=0)
//   par 1: passY -> pool -> passX   (exp issue starts at t=0)
// passY = self_y attention (y-only, 25% of exps); passX = e1,e2,e4 + combine.
// One block's pool latency hides under its neighbors' exp streams in BOTH
// generations — zero extra instructions, no occupancy cost, no cross-block
// sync. Retained from R3/R6: raw-only LDS, k-affine folded into per-query
// constants, v2f pk math, register double-buffered j-loops, shuffle minmax,
// padded LDS strides, XCD-swizzled contiguous columns (FETCH 141->104MB),
// obuf float4 flush, launch_bounds(256,5).

constexpr int B_SEQ = 128;
constexpr int N_COL = 8192;
constexpr int HWP   = 49;
constexpr int NT    = 256;
constexpr int TC    = 4;
constexpr int VSTR  = 132;   // value-array stride: spreads banks, rows 16B-aligned
constexpr int OSTR  = 5;     // obuf stride: gcd(5,32)=1 -> conflict-free

typedef float v2f __attribute__((ext_vector_type(2)));

#if __has_builtin(__builtin_elementwise_fma)
#define VFMA(a, b, c) __builtin_elementwise_fma((a), (b), (c))
#else
__device__ __forceinline__ v2f VFMA(v2f a, v2f b, v2f c) {
    v2f r; r.x = fmaf(a.x, b.x, c.x); r.y = fmaf(a.y, b.y, c.y); return r;
}
#endif

__global__ __launch_bounds__(NT, 5) void rsca_fused(
    const float* __restrict__ x, const float* __restrict__ y,
    const float* __restrict__ pwq, const float* __restrict__ pwk,
    const float* __restrict__ pwv, const float* __restrict__ pbq,
    const float* __restrict__ pbk, const float* __restrict__ pbv,
    const float* __restrict__ pwo, const float* __restrict__ pbo,
    float* __restrict__ out)
{
    __shared__ float xv[TC * VSTR];          // raw pooled means, [c*VSTR + j]
    __shared__ float yv[TC * VSTR];          // raw y,           [c*VSTR + j]
    __shared__ float pmnx[8][TC], pmxx[8][TC];   // x partials: pass*4+wave
    __shared__ float pmny[4][TC], pmxy[4][TC];   // y partials: wave
    __shared__ float obuf[2][B_SEQ * OSTR];

    const int t    = threadIdx.x;
    const int bid  = blockIdx.x;
    // same-XCD contiguous columns: 4 adjacent cg's (sharing a 64B out line)
    // are on one XCD -> L2 write-merge + L3 reuse of x across iterations.
    const int cg = (bid & 7) * ((N_COL / TC) >> 3) + (bid >> 3);
    const int n0 = cg * TC;
    // co-resident blocks on a CU = consecutive bid>>8 slots -> parity mixes
    // pool-phase and attn-phase blocks on every CU.
    const int par = (bid >> 8) & 1;

    const int ql   = t & 3;
    const int seg  = t >> 2;
    const int lane = t & 63;
    const int wid  = t >> 6;

    const float wq = pwq[0], wk = pwk[0], wv = pwv[0];
    const float bq = pbq[0], bk = pbk[0], bv = pbv[0];
    const float wo = pwo[0], bo = pbo[0];
    const float L2E = 1.4426950408889634f;
    const float wkL = wk * L2E, bkL = bk * L2E;
    const float alpha = wo * wv;
    const float beta2 = 2.0f * (wo * bv + bo);

    // ---- stage y (raw) + wave-partial min/max ----
    {
        const int j = t >> 2, c = t & 3;
        const float fy0 = y[(size_t)j * N_COL + n0 + c];
        const float fy1 = y[(size_t)(j + 64) * N_COL + n0 + c];
        yv[c * VSTR + j]      = fy0;
        yv[c * VSTR + j + 64] = fy1;
        float mn = fminf(fy0, fy1), mx = fmaxf(fy0, fy1);
        #pragma unroll
        for (int off = 4; off <= 32; off <<= 1) {
            mn = fminf(mn, __shfl_xor(mn, off));
            mx = fmaxf(mx, __shfl_xor(mx, off));
        }
        if (lane < 4) { pmny[wid][lane] = mn; pmxy[wid][lane] = mx; }
    }

    // ---- pool x -> xv (raw means) + wave-partial min/max ----
    auto pool_x = [&]() {
        for (int pass = 0; pass < 2; ++pass) {
            const int j = pass * 64 + seg;
            const float4* __restrict__ base =
                (const float4*)(x + ((size_t)j * N_COL + n0) * (size_t)HWP);
            float4 v[13];
            #pragma unroll
            for (int k = 0; k < 12; ++k) v[k] = base[ql + 4 * k];
            v[12] = base[48];

            float s0 = 0.f, s1 = 0.f, s2 = 0.f, s3 = 0.f;
            s0 += v[0].x + v[0].y + v[0].z + v[0].w;
            s0 += v[1].x + v[1].y + v[1].z + v[1].w;
            s0 += v[2].x + v[2].y + v[2].z + v[2].w;
            s1 += v[4].x + v[4].y + v[4].z + v[4].w;
            s1 += v[5].x + v[5].y + v[5].z + v[5].w;
            s2 += v[7].x + v[7].y + v[7].z + v[7].w;
            s2 += v[8].x + v[8].y + v[8].z + v[8].w;
            s3 += v[10].x + v[10].y + v[10].z + v[10].w;
            s3 += v[11].x + v[11].y + v[11].z + v[11].w;
            { const float sm = v[3].x + v[3].y + v[3].z + v[3].w;
              const float cr = (ql == 0) ? v[3].x : 0.0f;
              s0 += cr; s1 += sm - cr; }
            { const float sm = v[6].x + v[6].y + v[6].z + v[6].w;
              const float cr = (ql == 0) ? (v[6].x + v[6].y) : 0.0f;
              s1 += cr; s2 += sm - cr; }
            { const float sm = v[9].x + v[9].y + v[9].z + v[9].w;
              const float cr = (ql == 0) ? (v[9].x + v[9].y + v[9].z) : 0.0f;
              s2 += cr; s3 += sm - cr; }
            const float tail = v[12].x + v[12].y + v[12].z + v[12].w;

            s0 += __shfl_xor(s0, 1); s1 += __shfl_xor(s1, 1);
            s2 += __shfl_xor(s2, 1); s3 += __shfl_xor(s3, 1);
            s0 += __shfl_xor(s0, 2); s1 += __shfl_xor(s1, 2);
            s2 += __shfl_xor(s2, 2); s3 += __shfl_xor(s3, 2);
            float r = s0;
            r = (ql == 1) ? s1 : r;
            r = (ql == 2) ? s2 : r;
            r = (ql == 3) ? (s3 + tail) : r;
            const float mean = r * (1.0f / HWP);
            xv[ql * VSTR + j] = mean;

            float mn = mean, mx = mean;
            #pragma unroll
            for (int off = 4; off <= 32; off <<= 1) {
                mn = fminf(mn, __shfl_xor(mn, off));
                mx = fmaxf(mx, __shfl_xor(mx, off));
            }
            if (lane < 4) {
                pmnx[pass * 4 + wid][lane] = mn;
                pmxx[pass * 4 + wid][lane] = mx;
            }
        }
    };

    const int i  = t & (B_SEQ - 1);
    const int ch = t >> 7;

    if (par == 0) {
        pool_x();            // even slot: HBM streaming first
        __syncthreads();     // xv + yv ready
    } else {
        __syncthreads();     // yv ready for passY; pool comes after
    }

    // ---- passY: self_y attention (e3 = (qy, ky)), y-only ----
    v2f syS0[2], syS1[2];
    #pragma unroll
    for (int cc = 0; cc < 2; ++cc) {
        const int c = ch * 2 + cc;
        const float* __restrict__ vy = &yv[c * VSTR];
        float vymn = pmny[0][c], vymx = pmxy[0][c];
        #pragma unroll
        for (int s = 1; s < 4; ++s) {
            vymn = fminf(vymn, pmny[s][c]);
            vymx = fmaxf(vymx, pmxy[s][c]);
        }
        const float ayv = fmaf(vymx, wkL, bkL), byv = fmaf(vymn, wkL, bkL);
        const float kymx = fmaxf(ayv, byv), kymn = fminf(ayv, byv);

        const float yi = vy[i];
        const float qy = fmaf(yi, wq, bq);
        const float nmsy = -(qy >= 0.f ? qy * kymx : qy * kymn);
        const float qyw = qy * wkL;
        const v2f qyw2 = {qyw, qyw};
        const float csy = fmaf(qy, bkL, nmsy);
        const v2f csy2 = {csy, csy};

        v2f s0 = {0.f, 0.f}, s1 = {0.f, 0.f};
        auto pairY = [&](float v0, float v1) {
            const v2f vvj = {v0, v1};
            v2f t3 = VFMA(qyw2, vvj, csy2);
            v2f e3; e3.x = __builtin_amdgcn_exp2f(t3.x);
                    e3.y = __builtin_amdgcn_exp2f(t3.y);
            s1 = VFMA(e3, vvj, s1); s0 += e3;
        };
        float4 b0 = *(const float4*)&vy[0], b1 = *(const float4*)&vy[4];
        for (int j0 = 0; j0 < B_SEQ; j0 += 8) {
            const int jn = (j0 + 8) & (B_SEQ - 1);
            float4 nb0 = *(const float4*)&vy[jn];
            float4 nb1 = *(const float4*)&vy[jn + 4];
            pairY(b0.x, b0.y); pairY(b0.z, b0.w);
            pairY(b1.x, b1.y); pairY(b1.z, b1.w);
            b0 = nb0; b1 = nb1;
        }
        syS0[cc] = s0; syS1[cc] = s1;
    }

    if (par == 1) {
        pool_x();            // odd slot: pool under neighbors' attention
        __syncthreads();     // xv ready
    }

    // ---- passX: e1 (qx,kx), e2 (qy,kx), e4 (qx,ky) + combine ----
    #pragma unroll
    for (int cc = 0; cc < 2; ++cc) {
        const int c = ch * 2 + cc;
        const float* __restrict__ vx = &xv[c * VSTR];
        const float* __restrict__ vy = &yv[c * VSTR];

        float vxmn = pmnx[0][c], vxmx = pmxx[0][c];
        #pragma unroll
        for (int s = 1; s < 8; ++s) {
            vxmn = fminf(vxmn, pmnx[s][c]);
            vxmx = fmaxf(vxmx, pmxx[s][c]);
        }
        float vymn = pmny[0][c], vymx = pmxy[0][c];
        #pragma unroll
        for (int s = 1; s < 4; ++s) {
            vymn = fminf(vymn, pmny[s][c]);
            vymx = fmaxf(vymx, pmxy[s][c]);
        }
        const float axv = fmaf(vxmx, wkL, bkL), bxv = fmaf(vxmn, wkL, bkL);
        const float kxmx = fmaxf(axv, bxv), kxmn = fminf(axv, bxv);
        const float ayv = fmaf(vymx, wkL, bkL), byv = fmaf(vymn, wkL, bkL);
        const float kymx = fmaxf(ayv, byv), kymn = fminf(ayv, byv);

        const float xi = vx[i], yi = vy[i];
        const float qx = fmaf(xi, wq, bq), qy = fmaf(yi, wq, bq);
        const float nmsx = -(qx >= 0.f ? qx * kxmx : qx * kxmn);
        const float nmcy = -(qy >= 0.f ? qy * kxmx : qy * kxmn);
        const float nmcx = -(qx >= 0.f ? qx * kymx : qx * kymn);

        const float qxw = qx * wkL, qyw = qy * wkL;
        const v2f qxw2 = {qxw, qxw}, qyw2 = {qyw, qyw};
        const float csx = fmaf(qx, bkL, nmsx), ccy = fmaf(qy, bkL, nmcy);
        const float ccx = fmaf(qx, bkL, nmcx);
        const v2f csx2 = {csx, csx}, ccy2 = {ccy, ccy}, ccx2 = {ccx, ccx};

        v2f s0sx = {0.f, 0.f}, s1sx = {0.f, 0.f};
        v2f s0cy = {0.f, 0.f}, s1cy = {0.f, 0.f};
        v2f s0cx = {0.f, 0.f}, s1cx = {0.f, 0.f};

        auto pairX = [&](float v0, float v1) {     // kx pairs: e1 + e2
            const v2f vvj = {v0, v1};
            v2f t1 = VFMA(qxw2, vvj, csx2);
            v2f e1; e1.x = __builtin_amdgcn_exp2f(t1.x);
                    e1.y = __builtin_amdgcn_exp2f(t1.y);
            s1sx = VFMA(e1, vvj, s1sx); s0sx += e1;
            v2f t2 = VFMA(qyw2, vvj, ccy2);
            v2f e2; e2.x = __builtin_amdgcn_exp2f(t2.x);
                    e2.y = __builtin_amdgcn_exp2f(t2.y);
            s1cy = VFMA(e2, vvj, s1cy); s0cy += e2;
        };
        auto pairW = [&](float v0, float v1) {     // ky pairs: e4
            const v2f vvj = {v0, v1};
            v2f t4 = VFMA(qxw2, vvj, ccx2);
            v2f e4; e4.x = __builtin_amdgcn_exp2f(t4.x);
                    e4.y = __builtin_amdgcn_exp2f(t4.y);
            s1cx = VFMA(e4, vvj, s1cx); s0cx += e4;
        };

        float4 a0 = *(const float4*)&vx[0], a1 = *(const float4*)&vx[4];
        float4 b0 = *(const float4*)&vy[0], b1 = *(const float4*)&vy[4];
        for (int j0 = 0; j0 < B_SEQ; j0 += 8) {
            const int jn = (j0 + 8) & (B_SEQ - 1);
            float4 na0 = *(const float4*)&vx[jn];
            float4 na1 = *(const float4*)&vx[jn + 4];
            float4 nb0 = *(const float4*)&vy[jn];
            float4 nb1 = *(const float4*)&vy[jn + 4];

            pairX(a0.x, a0.y); pairX(a0.z, a0.w);
            pairX(a1.x, a1.y); pairX(a1.z, a1.w);
            pairW(b0.x, b0.y); pairW(b0.z, b0.w);
            pairW(b1.x, b1.y); pairW(b1.z, b1.w);

            a0 = na0; a1 = na1; b0 = nb0; b1 = nb1;
        }
        const float S0sx = s0sx.x + s0sx.y, S1sx = s1sx.x + s1sx.y;
        const float S0cy = s0cy.x + s0cy.y, S1cy = s1cy.x + s1cy.y;
        const float S0cx = s0cx.x + s0cx.y, S1cx = s1cx.x + s1cx.y;
        const float S0sy = syS0[cc].x + syS0[cc].y;
        const float S1sy = syS1[cc].x + syS1[cc].y;
        const float mx_attn = S1sx * __builtin_amdgcn_rcpf(S0sx)
                            + S1cx * __builtin_amdgcn_rcpf(S0cx);
        const float my_attn = S1sy * __builtin_amdgcn_rcpf(S0sy)
                            + S1cy * __builtin_amdgcn_rcpf(S0cy);
        obuf[0][i * OSTR + c] = fmaf(alpha, mx_attn, beta2 + xi);
        obuf[1][i * OSTR + c] = fmaf(alpha, my_attn, beta2 + yi);
    }
    __syncthreads();

    // ---- flush: one float4 per thread, 16B row segments (L2 merges 4 blocks
    // of the same XCD into 64B lines) ----
    {
        const int set = t >> 7;
        const int ii  = t & (B_SEQ - 1);
        const float* p = &obuf[set][ii * OSTR];
        float4 val;
        val.x = p[0]; val.y = p[1]; val.z = p[2]; val.w = p[3];
        *(float4*)&out[(size_t)ii * (2 * N_COL) + (size_t)set * N_COL + n0] = val;
    }
}

extern "C" void kernel_launch(void* const* d_in, const int* in_sizes, int n_in,
                              void* d_out, int out_size, void* d_ws, size_t ws_size,
                              hipStream_t stream) {
    const float* x   = (const float*)d_in[0];
    const float* y   = (const float*)d_in[1];
    const float* pwq = (const float*)d_in[2];
    const float* pwk = (const float*)d_in[3];
    const float* pwv = (const float*)d_in[4];
    const float* pbq = (const float*)d_in[5];
    const float* pbk = (const float*)d_in[6];
    const float* pbv = (const float*)d_in[7];
    const float* pwo = (const float*)d_in[8];
    const float* pbo = (const float*)d_in[9];
    float* out = (float*)d_out;

    rsca_fused<<<dim3(N_COL / TC), dim3(NT), 0, stream>>>(
        x, y, pwq, pwk, pwv, pbq, pbk, pbv, pwo, pbo, out);
}

// Round 8
// 316.578 us; speedup vs baseline: 1.0554x; 1.0070x over previous
//
#include <hip/hip_runtime.h>

// RSCA fully-fused, round-8. R7 parity phase-offset retained (best yet).
// New: column-fused attention loops. R7 ran each column's j-loop serially
// (cc unroll), capping per-wave ILP at one column's dependency chain while
// trans (~tens cyc) and LDS (~120 cyc) latencies recur per 8-j chunk. Now
// both columns (c0,c1) are processed in ONE j-loop: 16 independent exp
// chains per chunk, half the loop iterations. To stay under the VGPR=64
// occupancy cliff, passX is split into passX1 (e1+e2 over kx, both cols)
// and passX2 (e4 over ky, both cols); softmax partials are banked into
// obuf (LDS, thread-private addresses) between passes instead of registers:
//   passY  -> obuf[1] = sy_part
//   passX1 -> obuf[1] = final y-out (sy+cy), obuf[0] = sx_part
//   passX2 -> obuf[0] = final x-out (sx+cx)
// Retained: parity (par0 pool->attn, par1 passY->pool->passX), raw-only LDS,
// k-affine folded into per-query constants, v2f pk math, shuffle minmax,
// padded strides, XCD swizzle, float4 flush, launch_bounds(256,5).

constexpr int B_SEQ = 128;
constexpr int N_COL = 8192;
constexpr int HWP   = 49;
constexpr int NT    = 256;
constexpr int TC    = 4;
constexpr int VSTR  = 132;
constexpr int OSTR  = 5;

typedef float v2f __attribute__((ext_vector_type(2)));

#if __has_builtin(__builtin_elementwise_fma)
#define VFMA(a, b, c) __builtin_elementwise_fma((a), (b), (c))
#else
__device__ __forceinline__ v2f VFMA(v2f a, v2f b, v2f c) {
    v2f r; r.x = fmaf(a.x, b.x, c.x); r.y = fmaf(a.y, b.y, c.y); return r;
}
#endif

__global__ __launch_bounds__(NT, 5) void rsca_fused(
    const float* __restrict__ x, const float* __restrict__ y,
    const float* __restrict__ pwq, const float* __restrict__ pwk,
    const float* __restrict__ pwv, const float* __restrict__ pbq,
    const float* __restrict__ pbk, const float* __restrict__ pbv,
    const float* __restrict__ pwo, const float* __restrict__ pbo,
    float* __restrict__ out)
{
    __shared__ float xv[TC * VSTR];
    __shared__ float yv[TC * VSTR];
    __shared__ float pmnx[8][TC], pmxx[8][TC];
    __shared__ float pmny[4][TC], pmxy[4][TC];
    __shared__ float obuf[2][B_SEQ * OSTR];

    const int t    = threadIdx.x;
    const int bid  = blockIdx.x;
    const int cg = (bid & 7) * ((N_COL / TC) >> 3) + (bid >> 3);
    const int n0 = cg * TC;
    const int par = (bid >> 8) & 1;   // co-resident blocks mix parities per CU

    const int ql   = t & 3;
    const int seg  = t >> 2;
    const int lane = t & 63;
    const int wid  = t >> 6;

    const float wq = pwq[0], wk = pwk[0], wv = pwv[0];
    const float bq = pbq[0], bk = pbk[0], bv = pbv[0];
    const float wo = pwo[0], bo = pbo[0];
    const float L2E = 1.4426950408889634f;
    const float wkL = wk * L2E, bkL = bk * L2E;
    const float alpha = wo * wv;
    const float beta2 = 2.0f * (wo * bv + bo);

    // ---- stage y (raw) + wave-partial min/max ----
    {
        const int j = t >> 2, c = t & 3;
        const float fy0 = y[(size_t)j * N_COL + n0 + c];
        const float fy1 = y[(size_t)(j + 64) * N_COL + n0 + c];
        yv[c * VSTR + j]      = fy0;
        yv[c * VSTR + j + 64] = fy1;
        float mn = fminf(fy0, fy1), mx = fmaxf(fy0, fy1);
        #pragma unroll
        for (int off = 4; off <= 32; off <<= 1) {
            mn = fminf(mn, __shfl_xor(mn, off));
            mx = fmaxf(mx, __shfl_xor(mx, off));
        }
        if (lane < 4) { pmny[wid][lane] = mn; pmxy[wid][lane] = mx; }
    }

    // ---- pool x -> xv (raw means) + wave-partial min/max ----
    auto pool_x = [&]() {
        for (int pass = 0; pass < 2; ++pass) {
            const int j = pass * 64 + seg;
            const float4* __restrict__ base =
                (const float4*)(x + ((size_t)j * N_COL + n0) * (size_t)HWP);
            float4 v[13];
            #pragma unroll
            for (int k = 0; k < 12; ++k) v[k] = base[ql + 4 * k];
            v[12] = base[48];

            float s0 = 0.f, s1 = 0.f, s2 = 0.f, s3 = 0.f;
            s0 += v[0].x + v[0].y + v[0].z + v[0].w;
            s0 += v[1].x + v[1].y + v[1].z + v[1].w;
            s0 += v[2].x + v[2].y + v[2].z + v[2].w;
            s1 += v[4].x + v[4].y + v[4].z + v[4].w;
            s1 += v[5].x + v[5].y + v[5].z + v[5].w;
            s2 += v[7].x + v[7].y + v[7].z + v[7].w;
            s2 += v[8].x + v[8].y + v[8].z + v[8].w;
            s3 += v[10].x + v[10].y + v[10].z + v[10].w;
            s3 += v[11].x + v[11].y + v[11].z + v[11].w;
            { const float sm = v[3].x + v[3].y + v[3].z + v[3].w;
              const float cr = (ql == 0) ? v[3].x : 0.0f;
              s0 += cr; s1 += sm - cr; }
            { const float sm = v[6].x + v[6].y + v[6].z + v[6].w;
              const float cr = (ql == 0) ? (v[6].x + v[6].y) : 0.0f;
              s1 += cr; s2 += sm - cr; }
            { const float sm = v[9].x + v[9].y + v[9].z + v[9].w;
              const float cr = (ql == 0) ? (v[9].x + v[9].y + v[9].z) : 0.0f;
              s2 += cr; s3 += sm - cr; }
            const float tail = v[12].x + v[12].y + v[12].z + v[12].w;

            s0 += __shfl_xor(s0, 1); s1 += __shfl_xor(s1, 1);
            s2 += __shfl_xor(s2, 1); s3 += __shfl_xor(s3, 1);
            s0 += __shfl_xor(s0, 2); s1 += __shfl_xor(s1, 2);
            s2 += __shfl_xor(s2, 2); s3 += __shfl_xor(s3, 2);
            float r = s0;
            r = (ql == 1) ? s1 : r;
            r = (ql == 2) ? s2 : r;
            r = (ql == 3) ? (s3 + tail) : r;
            const float mean = r * (1.0f / HWP);
            xv[ql * VSTR + j] = mean;

            float mn = mean, mx = mean;
            #pragma unroll
            for (int off = 4; off <= 32; off <<= 1) {
                mn = fminf(mn, __shfl_xor(mn, off));
                mx = fmaxf(mx, __shfl_xor(mx, off));
            }
            if (lane < 4) {
                pmnx[pass * 4 + wid][lane] = mn;
                pmxx[pass * 4 + wid][lane] = mx;
            }
        }
    };

    const int i  = t & (B_SEQ - 1);
    const int ch = t >> 7;
    const int c0 = ch * 2, c1 = ch * 2 + 1;
    const float* __restrict__ vx0 = &xv[c0 * VSTR];
    const float* __restrict__ vx1 = &xv[c1 * VSTR];
    const float* __restrict__ vy0 = &yv[c0 * VSTR];
    const float* __restrict__ vy1 = &yv[c1 * VSTR];
    float* const po0y = &obuf[1][i * OSTR + c0];
    float* const po1y = &obuf[1][i * OSTR + c1];
    float* const po0x = &obuf[0][i * OSTR + c0];
    float* const po1x = &obuf[0][i * OSTR + c1];

    auto PAIR = [&](v2f& s0, v2f& s1, const v2f& qw, const v2f& cs,
                    float u0, float u1) {
        v2f vv = {u0, u1};
        v2f tt = VFMA(qw, vv, cs);
        v2f e; e.x = __builtin_amdgcn_exp2f(tt.x);
               e.y = __builtin_amdgcn_exp2f(tt.y);
        s1 = VFMA(e, vv, s1); s0 += e;
    };

    if (par == 0) pool_x();
    __syncthreads();

    // ---- ky bounds (persist: also needed by passX2) ----
    float vymn0 = pmny[0][c0], vymx0 = pmxy[0][c0];
    float vymn1 = pmny[0][c1], vymx1 = pmxy[0][c1];
    #pragma unroll
    for (int s = 1; s < 4; ++s) {
        vymn0 = fminf(vymn0, pmny[s][c0]); vymx0 = fmaxf(vymx0, pmxy[s][c0]);
        vymn1 = fminf(vymn1, pmny[s][c1]); vymx1 = fmaxf(vymx1, pmxy[s][c1]);
    }
    const float ay0 = fmaf(vymx0, wkL, bkL), by0 = fmaf(vymn0, wkL, bkL);
    const float kymx0 = fmaxf(ay0, by0), kymn0 = fminf(ay0, by0);
    const float ay1 = fmaf(vymx1, wkL, bkL), by1 = fmaf(vymn1, wkL, bkL);
    const float kymx1 = fmaxf(ay1, by1), kymn1 = fminf(ay1, by1);

    const float yi0 = vy0[i], yi1 = vy1[i];
    const float qy0 = fmaf(yi0, wq, bq), qy1 = fmaf(yi1, wq, bq);

    // ---- passY: e3 (qy, ky) both columns fused ----
    {
        const float nm0 = -(qy0 >= 0.f ? qy0 * kymx0 : qy0 * kymn0);
        const float nm1 = -(qy1 >= 0.f ? qy1 * kymx1 : qy1 * kymn1);
        const float qw0 = qy0 * wkL, qw1 = qy1 * wkL;
        const v2f qw20 = {qw0, qw0}, qw21 = {qw1, qw1};
        const float cs0 = fmaf(qy0, bkL, nm0), cs1 = fmaf(qy1, bkL, nm1);
        const v2f cs20 = {cs0, cs0}, cs21 = {cs1, cs1};

        v2f s00 = {0.f, 0.f}, s10 = {0.f, 0.f};
        v2f s01 = {0.f, 0.f}, s11 = {0.f, 0.f};
        for (int j0 = 0; j0 < B_SEQ; j0 += 8) {
            const float4 p00 = *(const float4*)&vy0[j0];
            const float4 p01 = *(const float4*)&vy0[j0 + 4];
            const float4 p10 = *(const float4*)&vy1[j0];
            const float4 p11 = *(const float4*)&vy1[j0 + 4];
            PAIR(s00, s10, qw20, cs20, p00.x, p00.y);
            PAIR(s01, s11, qw21, cs21, p10.x, p10.y);
            PAIR(s00, s10, qw20, cs20, p00.z, p00.w);
            PAIR(s01, s11, qw21, cs21, p10.z, p10.w);
            PAIR(s00, s10, qw20, cs20, p01.x, p01.y);
            PAIR(s01, s11, qw21, cs21, p11.x, p11.y);
            PAIR(s00, s10, qw20, cs20, p01.z, p01.w);
            PAIR(s01, s11, qw21, cs21, p11.z, p11.w);
        }
        *po0y = (s10.x + s10.y) * __builtin_amdgcn_rcpf(s00.x + s00.y);
        *po1y = (s11.x + s11.y) * __builtin_amdgcn_rcpf(s01.x + s01.y);
    }

    if (par == 1) { pool_x(); __syncthreads(); }

    // ---- kx bounds + queries from x ----
    float vxmn0 = pmnx[0][c0], vxmx0 = pmxx[0][c0];
    float vxmn1 = pmnx[0][c1], vxmx1 = pmxx[0][c1];
    #pragma unroll
    for (int s = 1; s < 8; ++s) {
        vxmn0 = fminf(vxmn0, pmnx[s][c0]); vxmx0 = fmaxf(vxmx0, pmxx[s][c0]);
        vxmn1 = fminf(vxmn1, pmnx[s][c1]); vxmx1 = fmaxf(vxmx1, pmxx[s][c1]);
    }
    const float ax0 = fmaf(vxmx0, wkL, bkL), bx0 = fmaf(vxmn0, wkL, bkL);
    const float kxmx0 = fmaxf(ax0, bx0), kxmn0 = fminf(ax0, bx0);
    const float ax1 = fmaf(vxmx1, wkL, bkL), bx1 = fmaf(vxmn1, wkL, bkL);
    const float kxmx1 = fmaxf(ax1, bx1), kxmn1 = fminf(ax1, bx1);

    const float xi0 = vx0[i], xi1 = vx1[i];
    const float qx0 = fmaf(xi0, wq, bq), qx1 = fmaf(xi1, wq, bq);

    // ---- passX1: e1 (qx,kx) + e2 (qy,kx), both columns fused ----
    {
        const float nms0 = -(qx0 >= 0.f ? qx0 * kxmx0 : qx0 * kxmn0);
        const float nms1 = -(qx1 >= 0.f ? qx1 * kxmx1 : qx1 * kxmn1);
        const float nmc0 = -(qy0 >= 0.f ? qy0 * kxmx0 : qy0 * kxmn0);
        const float nmc1 = -(qy1 >= 0.f ? qy1 * kxmx1 : qy1 * kxmn1);
        const float qwx0 = qx0 * wkL, qwx1 = qx1 * wkL;
        const float qwy0 = qy0 * wkL, qwy1 = qy1 * wkL;
        const v2f qwx20 = {qwx0, qwx0}, qwx21 = {qwx1, qwx1};
        const v2f qwy20 = {qwy0, qwy0}, qwy21 = {qwy1, qwy1};
        const float csa0 = fmaf(qx0, bkL, nms0), csa1 = fmaf(qx1, bkL, nms1);
        const float csb0 = fmaf(qy0, bkL, nmc0), csb1 = fmaf(qy1, bkL, nmc1);
        const v2f csa20 = {csa0, csa0}, csa21 = {csa1, csa1};
        const v2f csb20 = {csb0, csb0}, csb21 = {csb1, csb1};

        v2f sa00 = {0.f, 0.f}, sa10 = {0.f, 0.f};   // e1 col0
        v2f sb00 = {0.f, 0.f}, sb10 = {0.f, 0.f};   // e2 col0
        v2f sa01 = {0.f, 0.f}, sa11 = {0.f, 0.f};   // e1 col1
        v2f sb01 = {0.f, 0.f}, sb11 = {0.f, 0.f};   // e2 col1
        for (int j0 = 0; j0 < B_SEQ; j0 += 8) {
            const float4 p00 = *(const float4*)&vx0[j0];
            const float4 p01 = *(const float4*)&vx0[j0 + 4];
            const float4 p10 = *(const float4*)&vx1[j0];
            const float4 p11 = *(const float4*)&vx1[j0 + 4];
            PAIR(sa00, sa10, qwx20, csa20, p00.x, p00.y);
            PAIR(sb00, sb10, qwy20, csb20, p00.x, p00.y);
            PAIR(sa01, sa11, qwx21, csa21, p10.x, p10.y);
            PAIR(sb01, sb11, qwy21, csb21, p10.x, p10.y);
            PAIR(sa00, sa10, qwx20, csa20, p00.z, p00.w);
            PAIR(sb00, sb10, qwy20, csb20, p00.z, p00.w);
            PAIR(sa01, sa11, qwx21, csa21, p10.z, p10.w);
            PAIR(sb01, sb11, qwy21, csb21, p10.z, p10.w);
            PAIR(sa00, sa10, qwx20, csa20, p01.x, p01.y);
            PAIR(sb00, sb10, qwy20, csb20, p01.x, p01.y);
            PAIR(sa01, sa11, qwx21, csa21, p11.x, p11.y);
            PAIR(sb01, sb11, qwy21, csb21, p11.x, p11.y);
            PAIR(sa00, sa10, qwx20, csa20, p01.z, p01.w);
            PAIR(sb00, sb10, qwy20, csb20, p01.z, p01.w);
            PAIR(sa01, sa11, qwx21, csa21, p11.z, p11.w);
            PAIR(sb01, sb11, qwy21, csb21, p11.z, p11.w);
        }
        const float sx0 = (sa10.x + sa10.y) * __builtin_amdgcn_rcpf(sa00.x + sa00.y);
        const float sx1 = (sa11.x + sa11.y) * __builtin_amdgcn_rcpf(sa01.x + sa01.y);
        const float cy0 = (sb10.x + sb10.y) * __builtin_amdgcn_rcpf(sb00.x + sb00.y);
        const float cy1 = (sb11.x + sb11.y) * __builtin_amdgcn_rcpf(sb01.x + sb01.y);
        *po0y = fmaf(alpha, *po0y + cy0, beta2 + yi0);   // final y-out col0
        *po1y = fmaf(alpha, *po1y + cy1, beta2 + yi1);   // final y-out col1
        *po0x = sx0;                                      // stash sx partials
        *po1x = sx1;
    }

    // ---- passX2: e4 (qx, ky), both columns fused ----
    {
        const float nm0 = -(qx0 >= 0.f ? qx0 * kymx0 : qx0 * kymn0);
        const float nm1 = -(qx1 >= 0.f ? qx1 * kymx1 : qx1 * kymn1);
        const float qw0 = qx0 * wkL, qw1 = qx1 * wkL;
        const v2f qw20 = {qw0, qw0}, qw21 = {qw1, qw1};
        const float cs0 = fmaf(qx0, bkL, nm0), cs1 = fmaf(qx1, bkL, nm1);
        const v2f cs20 = {cs0, cs0}, cs21 = {cs1, cs1};

        v2f s00 = {0.f, 0.f}, s10 = {0.f, 0.f};
        v2f s01 = {0.f, 0.f}, s11 = {0.f, 0.f};
        for (int j0 = 0; j0 < B_SEQ; j0 += 8) {
            const float4 p00 = *(const float4*)&vy0[j0];
            const float4 p01 = *(const float4*)&vy0[j0 + 4];
            const float4 p10 = *(const float4*)&vy1[j0];
            const float4 p11 = *(const float4*)&vy1[j0 + 4];
            PAIR(s00, s10, qw20, cs20, p00.x, p00.y);
            PAIR(s01, s11, qw21, cs21, p10.x, p10.y);
            PAIR(s00, s10, qw20, cs20, p00.z, p00.w);
            PAIR(s01, s11, qw21, cs21, p10.z, p10.w);
            PAIR(s00, s10, qw20, cs20, p01.x, p01.y);
            PAIR(s01, s11, qw21, cs21, p11.x, p11.y);
            PAIR(s00, s10, qw20, cs20, p01.z, p01.w);
            PAIR(s01, s11, qw21, cs21, p11.z, p11.w);
        }
        const float cx0 = (s10.x + s10.y) * __builtin_amdgcn_rcpf(s00.x + s00.y);
        const float cx1 = (s11.x + s11.y) * __builtin_amdgcn_rcpf(s01.x + s01.y);
        *po0x = fmaf(alpha, *po0x + cx0, beta2 + xi0);   // final x-out col0
        *po1x = fmaf(alpha, *po1x + cx1, beta2 + xi1);   // final x-out col1
    }
    __syncthreads();

    // ---- flush: one float4 per thread, 16B row segments ----
    {
        const int set = t >> 7;
        const int ii  = t & (B_SEQ - 1);
        const float* p = &obuf[set][ii * OSTR];
        float4 val;
        val.x = p[0]; val.y = p[1]; val.z = p[2]; val.w = p[3];
        *(float4*)&out[(size_t)ii * (2 * N_COL) + (size_t)set * N_COL + n0] = val;
    }
}

extern "C" void kernel_launch(void* const* d_in, const int* in_sizes, int n_in,
                              void* d_out, int out_size, void* d_ws, size_t ws_size,
                              hipStream_t stream) {
    const float* x   = (const float*)d_in[0];
    const float* y   = (const float*)d_in[1];
    const float* pwq = (const float*)d_in[2];
    const float* pwk = (const float*)d_in[3];
    const float* pwv = (const float*)d_in[4];
    const float* pbq = (const float*)d_in[5];
    const float* pbk = (const float*)d_in[6];
    const float* pbv = (const float*)d_in[7];
    const float* pwo = (const float*)d_in[8];
    const float* pbo = (const float*)d_in[9];
    float* out = (float*)d_out;

    rsca_fused<<<dim3(N_COL / TC), dim3(NT), 0, stream>>>(
        x, y, pwq, pwk, pwv, pbq, pbk, pbv, pwo, pbo, out);
}